// Round 1
// baseline (280.656 us; speedup 1.0000x reference)
//
#include <hip/hip_runtime.h>

#define NQ 4
#define DEPTH 2
#define K 4           // batch elements per thread
#define BLK 256

typedef float v2f __attribute__((ext_vector_type(2)));

__device__ __forceinline__ float2 cmul(float2 a, float2 b) {
    return make_float2(a.x * b.x - a.y * b.y, a.x * b.y + a.y * b.x);
}
__device__ __forceinline__ float2 cadd(float2 a, float2 b) {
    return make_float2(a.x + b.x, a.y + b.y);
}

// One thread per K batch elements. Threads 0..15 of each block first build the
// fixed 16x16 circuit unitary U (post-encoding part) into LDS by simulating
// basis columns; then all threads evaluate phi = U * psi(x) for their elements.
__global__ __launch_bounds__(BLK) void vqc_kernel(const float* __restrict__ x,
                                                  const float* __restrict__ qw,
                                                  float* __restrict__ out, int B) {
    __shared__ v2f Um[16][16];   // Um[i][j] = (Re U[i][j], Im U[i][j])

    const int tid = threadIdx.x;

    if (tid < 16) {
        // Simulate column `tid` of the fixed unitary: layers of Rot + CNOT ring.
        float2 amp[16];
#pragma unroll
        for (int i = 0; i < 16; i++)
            amp[i] = make_float2((i == tid) ? 1.f : 0.f, 0.f);

#pragma unroll
        for (int layer = 0; layer < DEPTH; layer++) {
#pragma unroll
            for (int w = 0; w < NQ; w++) {
                const float* g = qw + (layer * NQ + w) * 3;
                float phi = g[0], theta = g[1], omega = g[2];
                float ch, sh, sp, cp, sm, cm;
                __sincosf(0.5f * theta, &sh, &ch);
                __sincosf(-0.5f * (phi + omega), &sp, &cp);   // ep = exp(-i(phi+omega)/2)
                __sincosf(0.5f * (phi - omega), &sm, &cm);    // em = exp(+i(phi-omega)/2)
                float2 U00 = make_float2(cp * ch, sp * ch);
                float2 U01 = make_float2(-cm * sh, -sm * sh);
                float2 U10 = make_float2(cm * sh, -sm * sh);  // conj(em)*s
                float2 U11 = make_float2(cp * ch, -sp * ch);  // conj(ep)*c
                const int mask = 8 >> w;                      // wire w = bit (3-w)
#pragma unroll
                for (int i0 = 0; i0 < 16; i0++) {
                    if (i0 & mask) continue;
                    const int i1 = i0 | mask;
                    float2 a0 = amp[i0], a1 = amp[i1];
                    amp[i0] = cadd(cmul(U00, a0), cmul(U01, a1));
                    amp[i1] = cadd(cmul(U10, a0), cmul(U11, a1));
                }
            }
            // CNOT ring: (0,1),(1,2),(2,3),(3,0)
#pragma unroll
            for (int c = 0; c < NQ; c++) {
                const int t = (c + 1) & 3;
                const int cmsk = 8 >> c, tmsk = 8 >> t;
#pragma unroll
                for (int i = 0; i < 16; i++) {
                    if ((i & cmsk) && !(i & tmsk)) {
                        float2 tmp = amp[i];
                        amp[i] = amp[i | tmsk];
                        amp[i | tmsk] = tmp;
                    }
                }
            }
        }
#pragma unroll
        for (int i = 0; i < 16; i++) {
            v2f u; u.x = amp[i].x; u.y = amp[i].y;
            Um[i][tid] = u;
        }
    }
    __syncthreads();

    const int base = blockIdx.x * (BLK * K) + tid;

    // psi for K elements: real product state from the RY encoding
    float psi[K][16];
    bool valid[K];
#pragma unroll
    for (int k = 0; k < K; k++) {
        const int b = base + k * BLK;
        valid[k] = (b < B);
        float4 xv = valid[k] ? ((const float4*)x)[b] : make_float4(0.f, 0.f, 0.f, 0.f);
        float c0, s0, c1, s1, c2, s2, c3, s3;
        __sincosf(0.5f * xv.x, &s0, &c0);
        __sincosf(0.5f * xv.y, &s1, &c1);
        __sincosf(0.5f * xv.z, &s2, &c2);
        __sincosf(0.5f * xv.w, &s3, &c3);
        const float a01[4] = {c0 * c1, c0 * s1, s0 * c1, s0 * s1};
        const float a23[4] = {c2 * c3, c2 * s3, s2 * c3, s2 * s3};
#pragma unroll
        for (int i = 0; i < 16; i++)
            psi[k][i] = a01[i >> 2] * a23[i & 3];
    }

    float ow[NQ][K];
#pragma unroll
    for (int w = 0; w < NQ; w++)
#pragma unroll
        for (int k = 0; k < K; k++) ow[w][k] = 0.f;

#pragma unroll
    for (int i = 0; i < 16; i++) {
        v2f acc[K];
#pragma unroll
        for (int k = 0; k < K; k++) acc[k] = (v2f)0.f;
#pragma unroll
        for (int j = 0; j < 16; j++) {
            const v2f u = Um[i][j];      // wave-uniform broadcast from LDS
#pragma unroll
            for (int k = 0; k < K; k++)
                acc[k] += u * psi[k][j]; // -> v_pk_fma_f32 (Re/Im packed)
        }
#pragma unroll
        for (int k = 0; k < K; k++) {
            const float p = acc[k].x * acc[k].x + acc[k].y * acc[k].y;
            ow[0][k] += (i & 8) ? -p : p;
            ow[1][k] += (i & 4) ? -p : p;
            ow[2][k] += (i & 2) ? -p : p;
            ow[3][k] += (i & 1) ? -p : p;
        }
    }

#pragma unroll
    for (int k = 0; k < K; k++) {
        const int b = base + k * BLK;
        if (valid[k])
            ((float4*)out)[b] = make_float4(ow[0][k], ow[1][k], ow[2][k], ow[3][k]);
    }
}

extern "C" void kernel_launch(void* const* d_in, const int* in_sizes, int n_in,
                              void* d_out, int out_size, void* d_ws, size_t ws_size,
                              hipStream_t stream) {
    const float* x  = (const float*)d_in[0];
    const float* qw = (const float*)d_in[1];
    float* out = (float*)d_out;
    const int B = in_sizes[0] / NQ;
    const int blocks = (B + BLK * K - 1) / (BLK * K);
    vqc_kernel<<<blocks, BLK, 0, stream>>>(x, qw, out, B);
}

// Round 2
// 113.744 us; speedup vs baseline: 2.4674x; 2.4674x over previous
//
#include <hip/hip_runtime.h>

#define NQ 4
#define DEPTH 2
#define K 4           // batch elements per thread
#define BLK 256

typedef float v2f __attribute__((ext_vector_type(2)));

__device__ __forceinline__ float2 cmul(float2 a, float2 b) {
    return make_float2(a.x * b.x - a.y * b.y, a.x * b.y + a.y * b.x);
}
__device__ __forceinline__ float2 cadd(float2 a, float2 b) {
    return make_float2(a.x + b.x, a.y + b.y);
}

// Simulate basis column `col` of the fixed post-encoding circuit unitary.
__device__ __forceinline__ void build_u_col(const float* __restrict__ qw, int col,
                                            float2 amp[16]) {
#pragma unroll
    for (int i = 0; i < 16; i++)
        amp[i] = make_float2((i == col) ? 1.f : 0.f, 0.f);

#pragma unroll
    for (int layer = 0; layer < DEPTH; layer++) {
#pragma unroll
        for (int w = 0; w < NQ; w++) {
            const float* g = qw + (layer * NQ + w) * 3;
            float phi = g[0], theta = g[1], omega = g[2];
            float ch, sh, sp, cp, sm, cm;
            __sincosf(0.5f * theta, &sh, &ch);
            __sincosf(-0.5f * (phi + omega), &sp, &cp);   // ep = exp(-i(phi+omega)/2)
            __sincosf(0.5f * (phi - omega), &sm, &cm);    // em = exp(+i(phi-omega)/2)
            float2 U00 = make_float2(cp * ch, sp * ch);
            float2 U01 = make_float2(-cm * sh, -sm * sh);
            float2 U10 = make_float2(cm * sh, -sm * sh);  // conj(em)*s
            float2 U11 = make_float2(cp * ch, -sp * ch);  // conj(ep)*c
            const int mask = 8 >> w;                      // wire w = bit (3-w)
#pragma unroll
            for (int i0 = 0; i0 < 16; i0++) {
                if (i0 & mask) continue;
                const int i1 = i0 | mask;
                float2 a0 = amp[i0], a1 = amp[i1];
                amp[i0] = cadd(cmul(U00, a0), cmul(U01, a1));
                amp[i1] = cadd(cmul(U10, a0), cmul(U11, a1));
            }
        }
        // CNOT ring: (0,1),(1,2),(2,3),(3,0)
#pragma unroll
        for (int c = 0; c < NQ; c++) {
            const int t = (c + 1) & 3;
            const int cmsk = 8 >> c, tmsk = 8 >> t;
#pragma unroll
            for (int i = 0; i < 16; i++) {
                if ((i & cmsk) && !(i & tmsk)) {
                    float2 tmp = amp[i];
                    amp[i] = amp[i | tmsk];
                    amp[i | tmsk] = tmp;
                }
            }
        }
    }
}

// Kernel A: one tiny block computes U (16x16 complex) into global scratch.
__global__ void build_u_kernel(const float* __restrict__ qw, v2f* __restrict__ Ug) {
    const int tid = threadIdx.x;
    if (tid < 16) {
        float2 amp[16];
        build_u_col(qw, tid, amp);
#pragma unroll
        for (int i = 0; i < 16; i++) {
            v2f u; u.x = amp[i].x; u.y = amp[i].y;
            Ug[i * 16 + tid] = u;   // row-major [i][j]
        }
    }
}

// Shared main path: Um is 2 KB LDS holding U row-major as v2f[256].
__device__ __forceinline__ void vqc_main_body(const float* __restrict__ x,
                                              const v2f* Um,
                                              float* __restrict__ out, int B) {
    const int tid = threadIdx.x;
    const int base = blockIdx.x * (BLK * K) + tid;

    // psi for K elements: real product state from the RY encoding
    float psi[K][16];
    bool valid[K];
#pragma unroll
    for (int k = 0; k < K; k++) {
        const int b = base + k * BLK;
        valid[k] = (b < B);
        float4 xv = valid[k] ? ((const float4*)x)[b] : make_float4(0.f, 0.f, 0.f, 0.f);
        float c0, s0, c1, s1, c2, s2, c3, s3;
        __sincosf(0.5f * xv.x, &s0, &c0);
        __sincosf(0.5f * xv.y, &s1, &c1);
        __sincosf(0.5f * xv.z, &s2, &c2);
        __sincosf(0.5f * xv.w, &s3, &c3);
        const float a01[4] = {c0 * c1, c0 * s1, s0 * c1, s0 * s1};
        const float a23[4] = {c2 * c3, c2 * s3, s2 * c3, s2 * s3};
#pragma unroll
        for (int i = 0; i < 16; i++)
            psi[k][i] = a01[i >> 2] * a23[i & 3];
    }

    float ow[NQ][K];
#pragma unroll
    for (int w = 0; w < NQ; w++)
#pragma unroll
        for (int k = 0; k < K; k++) ow[w][k] = 0.f;

    // Process rows i in quads; Walsh-combine the signed prob sums.
#pragma unroll 1
    for (int iq = 0; iq < 4; iq++) {
        v2f acc[4][K];
#pragma unroll
        for (int ii = 0; ii < 4; ii++)
#pragma unroll
            for (int k = 0; k < K; k++) acc[ii][k] = (v2f)0.f;

        const v2f* Urow = Um + iq * 64;
#pragma unroll
        for (int j = 0; j < 16; j++) {
#pragma unroll
            for (int ii = 0; ii < 4; ii++) {
                const v2f u = Urow[ii * 16 + j];   // wave-uniform LDS broadcast
#pragma unroll
                for (int k = 0; k < K; k++)
                    acc[ii][k] += u * psi[k][j];   // v_pk_fma_f32
            }
        }

        const float sg0 = (iq & 2) ? -1.f : 1.f;   // bit3 of i
        const float sg1 = (iq & 1) ? -1.f : 1.f;   // bit2 of i
#pragma unroll
        for (int k = 0; k < K; k++) {
            float p0 = acc[0][k].x * acc[0][k].x + acc[0][k].y * acc[0][k].y;
            float p1 = acc[1][k].x * acc[1][k].x + acc[1][k].y * acc[1][k].y;
            float p2 = acc[2][k].x * acc[2][k].x + acc[2][k].y * acc[2][k].y;
            float p3 = acc[3][k].x * acc[3][k].x + acc[3][k].y * acc[3][k].y;
            float s01 = p0 + p1, d01 = p0 - p1;
            float s23 = p2 + p3, d23 = p2 - p3;
            float ssum = s01 + s23;
            ow[2][k] += s01 - s23;   // sign from bit1 (ii&2)
            ow[3][k] += d01 + d23;   // sign from bit0 (ii&1)
            ow[0][k] = fmaf(sg0, ssum, ow[0][k]);
            ow[1][k] = fmaf(sg1, ssum, ow[1][k]);
        }
    }

#pragma unroll
    for (int k = 0; k < K; k++) {
        const int b = base + k * BLK;
        if (valid[k])
            ((float4*)out)[b] = make_float4(ow[0][k], ow[1][k], ow[2][k], ow[3][k]);
    }
}

// Kernel B: load precomputed U from global scratch into LDS, run main path.
__global__ __launch_bounds__(BLK) void vqc_main(const float* __restrict__ x,
                                                const v2f* __restrict__ Ug,
                                                float* __restrict__ out, int B) {
    __shared__ v2f Um[256];
    Um[threadIdx.x] = Ug[threadIdx.x];
    __syncthreads();
    vqc_main_body(x, Um, out, B);
}

// Fallback (ws too small): build U in-block like round 1. Register-isolated
// in its own kernel so the builder can't inflate vqc_main's allocation.
__global__ __launch_bounds__(BLK) void vqc_fused(const float* __restrict__ x,
                                                 const float* __restrict__ qw,
                                                 float* __restrict__ out, int B) {
    __shared__ v2f Um[256];
    if (threadIdx.x < 16) {
        float2 amp[16];
        build_u_col(qw, threadIdx.x, amp);
#pragma unroll
        for (int i = 0; i < 16; i++) {
            v2f u; u.x = amp[i].x; u.y = amp[i].y;
            Um[i * 16 + threadIdx.x] = u;
        }
    }
    __syncthreads();
    vqc_main_body(x, Um, out, B);
}

extern "C" void kernel_launch(void* const* d_in, const int* in_sizes, int n_in,
                              void* d_out, int out_size, void* d_ws, size_t ws_size,
                              hipStream_t stream) {
    const float* x  = (const float*)d_in[0];
    const float* qw = (const float*)d_in[1];
    float* out = (float*)d_out;
    const int B = in_sizes[0] / NQ;
    const int blocks = (B + BLK * K - 1) / (BLK * K);

    if (ws_size >= 256 * sizeof(v2f)) {
        v2f* Ug = (v2f*)d_ws;
        build_u_kernel<<<1, 64, 0, stream>>>(qw, Ug);
        vqc_main<<<blocks, BLK, 0, stream>>>(x, Ug, out, B);
    } else {
        vqc_fused<<<blocks, BLK, 0, stream>>>(x, qw, out, B);
    }
}

// Round 3
// 110.059 us; speedup vs baseline: 2.5501x; 1.0335x over previous
//
#include <hip/hip_runtime.h>

#define NQ 4
#define DEPTH 2
#define BLK 256
#define K 4           // elements per thread = 2 element-pairs packed in pk lanes

typedef float v2f __attribute__((ext_vector_type(2)));
typedef float v4f __attribute__((ext_vector_type(4)));

// ---- forced packed-fp32 math (compiler won't auto-form v_pk_fma_f32) ----
// d = {u.lo*b.lo + d.lo, u.lo*b.hi + d.hi}   (broadcast LOW half of u)
__device__ __forceinline__ void pk_fma_lo(v2f& acc, v2f u, v2f b) {
    asm("v_pk_fma_f32 %0, %1, %2, %0 op_sel:[0,0,0] op_sel_hi:[0,1,1]"
        : "+v"(acc) : "v"(u), "v"(b));
}
// d = {u.hi*b.lo + d.lo, u.hi*b.hi + d.hi}   (broadcast HIGH half of u)
__device__ __forceinline__ void pk_fma_hi(v2f& acc, v2f u, v2f b) {
    asm("v_pk_fma_f32 %0, %1, %2, %0 op_sel:[1,0,0] op_sel_hi:[1,1,1]"
        : "+v"(acc) : "v"(u), "v"(b));
}
__device__ __forceinline__ v2f pk_mul(v2f a, v2f b) {
    v2f d;
    asm("v_pk_mul_f32 %0, %1, %2" : "=v"(d) : "v"(a), "v"(b));
    return d;
}
__device__ __forceinline__ void pk_fma(v2f& acc, v2f a, v2f b) {
    asm("v_pk_fma_f32 %0, %1, %2, %0" : "+v"(acc) : "v"(a), "v"(b));
}

__device__ __forceinline__ float2 cmul(float2 a, float2 b) {
    return make_float2(a.x * b.x - a.y * b.y, a.x * b.y + a.y * b.x);
}
__device__ __forceinline__ float2 cadd(float2 a, float2 b) {
    return make_float2(a.x + b.x, a.y + b.y);
}

// Simulate basis column `col` of the fixed post-encoding circuit unitary.
__device__ __forceinline__ void build_u_col(const float* __restrict__ qw, int col,
                                            float2 amp[16]) {
#pragma unroll
    for (int i = 0; i < 16; i++)
        amp[i] = make_float2((i == col) ? 1.f : 0.f, 0.f);

#pragma unroll
    for (int layer = 0; layer < DEPTH; layer++) {
#pragma unroll
        for (int w = 0; w < NQ; w++) {
            const float* g = qw + (layer * NQ + w) * 3;
            float phi = g[0], theta = g[1], omega = g[2];
            float ch, sh, sp, cp, sm, cm;
            __sincosf(0.5f * theta, &sh, &ch);
            __sincosf(-0.5f * (phi + omega), &sp, &cp);
            __sincosf(0.5f * (phi - omega), &sm, &cm);
            float2 U00 = make_float2(cp * ch, sp * ch);
            float2 U01 = make_float2(-cm * sh, -sm * sh);
            float2 U10 = make_float2(cm * sh, -sm * sh);
            float2 U11 = make_float2(cp * ch, -sp * ch);
            const int mask = 8 >> w;
#pragma unroll
            for (int i0 = 0; i0 < 16; i0++) {
                if (i0 & mask) continue;
                const int i1 = i0 | mask;
                float2 a0 = amp[i0], a1 = amp[i1];
                amp[i0] = cadd(cmul(U00, a0), cmul(U01, a1));
                amp[i1] = cadd(cmul(U10, a0), cmul(U11, a1));
            }
        }
#pragma unroll
        for (int c = 0; c < NQ; c++) {
            const int t = (c + 1) & 3;
            const int cmsk = 8 >> c, tmsk = 8 >> t;
#pragma unroll
            for (int i = 0; i < 16; i++) {
                if ((i & cmsk) && !(i & tmsk)) {
                    float2 tmp = amp[i];
                    amp[i] = amp[i | tmsk];
                    amp[i | tmsk] = tmp;
                }
            }
        }
    }
}

// Kernel A: one tiny block computes U (16x16 complex) into global scratch.
__global__ void build_u_kernel(const float* __restrict__ qw, v2f* __restrict__ Ug) {
    const int tid = threadIdx.x;
    if (tid < 16) {
        float2 amp[16];
        build_u_col(qw, tid, amp);
#pragma unroll
        for (int i = 0; i < 16; i++) {
            v2f u; u.x = amp[i].x; u.y = amp[i].y;
            Ug[i * 16 + tid] = u;   // row-major [i][j]
        }
    }
}

// ---- main path: Um in LDS as v4f[128] (2 complex entries per slot) ----
__device__ __forceinline__ void vqc_main_body(const float* __restrict__ x,
                                              const v4f* UmS,
                                              float* __restrict__ out, int B) {
    const int tid = threadIdx.x;
    const int base = blockIdx.x * (BLK * K) + tid;

    float4 xv[K];
    bool val[K];
#pragma unroll
    for (int k = 0; k < K; k++) {
        const int b = base + k * BLK;
        val[k] = (b < B);
        xv[k] = val[k] ? ((const float4*)x)[b] : make_float4(0.f, 0.f, 0.f, 0.f);
    }

    // RY encoding: per element, tensor factors over wires (0,1) and (2,3).
    const float R = 0.07957747154594767f;   // 1/(4*pi): sin(x/2)=v_sin(x*R)
    float a01[K][4], a23[K][4];
#pragma unroll
    for (int k = 0; k < K; k++) {
        float s0 = __builtin_amdgcn_sinf(xv[k].x * R), c0 = __builtin_amdgcn_cosf(xv[k].x * R);
        float s1 = __builtin_amdgcn_sinf(xv[k].y * R), c1 = __builtin_amdgcn_cosf(xv[k].y * R);
        float s2 = __builtin_amdgcn_sinf(xv[k].z * R), c2 = __builtin_amdgcn_cosf(xv[k].z * R);
        float s3 = __builtin_amdgcn_sinf(xv[k].w * R), c3 = __builtin_amdgcn_cosf(xv[k].w * R);
        a01[k][0] = c0 * c1; a01[k][1] = c0 * s1; a01[k][2] = s0 * c1; a01[k][3] = s0 * s1;
        a23[k][0] = c2 * c3; a23[k][1] = c2 * s3; a23[k][2] = s2 * c3; a23[k][3] = s2 * s3;
    }
    // pack element-pairs into pk lanes: pair p = elements (2p, 2p+1)
    v2f a01p[2][4], a23p[2][4];
#pragma unroll
    for (int p = 0; p < 2; p++)
#pragma unroll
        for (int i = 0; i < 4; i++) {
            v2f t0; t0.x = a01[2 * p][i]; t0.y = a01[2 * p + 1][i]; a01p[p][i] = t0;
            v2f t1; t1.x = a23[2 * p][i]; t1.y = a23[2 * p + 1][i]; a23p[p][i] = t1;
        }

    v2f ow[4][2];   // [out wire][pair], lanes = elements
#pragma unroll
    for (int w = 0; w < 4; w++)
#pragma unroll
        for (int p = 0; p < 2; p++) ow[w][p] = (v2f)0.f;

#pragma unroll 1
    for (int iq = 0; iq < 4; iq++) {
        const v4f* rowp = UmS + iq * 32;      // 4 rows x 8 quads
        v2f accre[4][2], accim[4][2];
#pragma unroll
        for (int ii = 0; ii < 4; ii++)
#pragma unroll
            for (int p = 0; p < 2; p++) { accre[ii][p] = (v2f)0.f; accim[ii][p] = (v2f)0.f; }

#pragma unroll
        for (int jp = 0; jp < 8; jp++) {
            const int j0 = 2 * jp, j1 = 2 * jp + 1;
            v2f ps0[2], ps1[2];
#pragma unroll
            for (int p = 0; p < 2; p++) {
                ps0[p] = pk_mul(a01p[p][j0 >> 2], a23p[p][j0 & 3]);
                ps1[p] = pk_mul(a01p[p][j1 >> 2], a23p[p][j1 & 3]);
            }
#pragma unroll
            for (int ii = 0; ii < 4; ii++) {
                v4f q = rowp[ii * 8 + jp];                        // ds_read_b128
                v2f u0 = __builtin_shufflevector(q, q, 0, 1);     // {re,im} of col j0
                v2f u1 = __builtin_shufflevector(q, q, 2, 3);     // {re,im} of col j1
#pragma unroll
                for (int p = 0; p < 2; p++) {
                    pk_fma_lo(accre[ii][p], u0, ps0[p]);
                    pk_fma_hi(accim[ii][p], u0, ps0[p]);
                    pk_fma_lo(accre[ii][p], u1, ps1[p]);
                    pk_fma_hi(accim[ii][p], u1, ps1[p]);
                }
            }
        }

        // probs (packed over elements) + Walsh combine
#pragma unroll
        for (int p = 0; p < 2; p++) {
            v2f p0 = pk_mul(accre[0][p], accre[0][p]); pk_fma(p0, accim[0][p], accim[0][p]);
            v2f p1 = pk_mul(accre[1][p], accre[1][p]); pk_fma(p1, accim[1][p], accim[1][p]);
            v2f p2 = pk_mul(accre[2][p], accre[2][p]); pk_fma(p2, accim[2][p], accim[2][p]);
            v2f p3 = pk_mul(accre[3][p], accre[3][p]); pk_fma(p3, accim[3][p], accim[3][p]);
            v2f s01 = p0 + p1, d01 = p0 - p1;
            v2f s23 = p2 + p3, d23 = p2 - p3;
            v2f ssum = s01 + s23;
            ow[2][p] += s01 - s23;     // sign from bit1 of row
            ow[3][p] += d01 + d23;     // sign from bit0 of row
            if (iq & 2) ow[0][p] -= ssum; else ow[0][p] += ssum;   // bit3
            if (iq & 1) ow[1][p] -= ssum; else ow[1][p] += ssum;   // bit2
        }
    }

#pragma unroll
    for (int p = 0; p < 2; p++)
#pragma unroll
        for (int e = 0; e < 2; e++) {
            const int k = 2 * p + e;
            const int b = base + k * BLK;
            if (val[k]) {
                float4 o;
                o.x = (e == 0) ? ow[0][p].x : ow[0][p].y;
                o.y = (e == 0) ? ow[1][p].x : ow[1][p].y;
                o.z = (e == 0) ? ow[2][p].x : ow[2][p].y;
                o.w = (e == 0) ? ow[3][p].x : ow[3][p].y;
                ((float4*)out)[b] = o;
            }
        }
}

// Kernel B: stage precomputed U into LDS, run main path.
__global__ __launch_bounds__(BLK, 4) void vqc_main(const float* __restrict__ x,
                                                   const v4f* __restrict__ Ug,
                                                   float* __restrict__ out, int B) {
    __shared__ v4f UmS[128];
    if (threadIdx.x < 128) UmS[threadIdx.x] = Ug[threadIdx.x];
    __syncthreads();
    vqc_main_body(x, UmS, out, B);
}

// Fallback if ws is too small: build U in-block (slow path, normally unused).
__global__ void vqc_fused(const float* __restrict__ x, const float* __restrict__ qw,
                          float* __restrict__ out, int B) {
    __shared__ v4f UmS[128];
    if (threadIdx.x < 16) {
        float2 amp[16];
        build_u_col(qw, threadIdx.x, amp);
        v2f* Um2 = (v2f*)UmS;
#pragma unroll
        for (int i = 0; i < 16; i++) {
            v2f u; u.x = amp[i].x; u.y = amp[i].y;
            Um2[i * 16 + threadIdx.x] = u;
        }
    }
    __syncthreads();
    vqc_main_body(x, UmS, out, B);
}

extern "C" void kernel_launch(void* const* d_in, const int* in_sizes, int n_in,
                              void* d_out, int out_size, void* d_ws, size_t ws_size,
                              hipStream_t stream) {
    const float* x  = (const float*)d_in[0];
    const float* qw = (const float*)d_in[1];
    float* out = (float*)d_out;
    const int B = in_sizes[0] / NQ;
    const int blocks = (B + BLK * K - 1) / (BLK * K);

    if (ws_size >= 256 * sizeof(v2f)) {
        v2f* Ug = (v2f*)d_ws;
        build_u_kernel<<<1, 64, 0, stream>>>(qw, Ug);
        vqc_main<<<blocks, BLK, 0, stream>>>(x, (const v4f*)Ug, out, B);
    } else {
        vqc_fused<<<blocks, BLK, 0, stream>>>(x, qw, out, B);
    }
}

// Round 4
// 107.349 us; speedup vs baseline: 2.6144x; 1.0252x over previous
//
#include <hip/hip_runtime.h>

#define NQ 4
#define DEPTH 2
#define BLK 256
#define K 4           // elements per thread = 2 element-pairs packed in pk lanes

typedef float v2f __attribute__((ext_vector_type(2)));
typedef float v4f __attribute__((ext_vector_type(4)));

// ---- forced packed-fp32 math ----
// u is wave-uniform {re,im}: "s" places it in an SGPR pair (free if the load
// scalarized; VOP3P allows exactly one scalar source).
__device__ __forceinline__ void pk_fma_lo_s(v2f& acc, v2f u, v2f b) {
    asm("v_pk_fma_f32 %0, %1, %2, %0 op_sel:[0,0,0] op_sel_hi:[0,1,1]"
        : "+v"(acc) : "s"(u), "v"(b));
}
__device__ __forceinline__ void pk_fma_hi_s(v2f& acc, v2f u, v2f b) {
    asm("v_pk_fma_f32 %0, %1, %2, %0 op_sel:[1,0,0] op_sel_hi:[1,1,1]"
        : "+v"(acc) : "s"(u), "v"(b));
}
__device__ __forceinline__ v2f pk_mul(v2f a, v2f b) {
    v2f d;
    asm("v_pk_mul_f32 %0, %1, %2" : "=v"(d) : "v"(a), "v"(b));
    return d;
}
__device__ __forceinline__ void pk_fma(v2f& acc, v2f a, v2f b) {
    asm("v_pk_fma_f32 %0, %1, %2, %0" : "+v"(acc) : "v"(a), "v"(b));
}

__device__ __forceinline__ float2 cmul(float2 a, float2 b) {
    return make_float2(a.x * b.x - a.y * b.y, a.x * b.y + a.y * b.x);
}
__device__ __forceinline__ float2 cadd(float2 a, float2 b) {
    return make_float2(a.x + b.x, a.y + b.y);
}

// Simulate basis column `col` of the fixed post-encoding circuit unitary.
__device__ __forceinline__ void build_u_col(const float* __restrict__ qw, int col,
                                            float2 amp[16]) {
#pragma unroll
    for (int i = 0; i < 16; i++)
        amp[i] = make_float2((i == col) ? 1.f : 0.f, 0.f);

#pragma unroll
    for (int layer = 0; layer < DEPTH; layer++) {
#pragma unroll
        for (int w = 0; w < NQ; w++) {
            const float* g = qw + (layer * NQ + w) * 3;
            float phi = g[0], theta = g[1], omega = g[2];
            float ch, sh, sp, cp, sm, cm;
            __sincosf(0.5f * theta, &sh, &ch);
            __sincosf(-0.5f * (phi + omega), &sp, &cp);
            __sincosf(0.5f * (phi - omega), &sm, &cm);
            float2 U00 = make_float2(cp * ch, sp * ch);
            float2 U01 = make_float2(-cm * sh, -sm * sh);
            float2 U10 = make_float2(cm * sh, -sm * sh);
            float2 U11 = make_float2(cp * ch, -sp * ch);
            const int mask = 8 >> w;
#pragma unroll
            for (int i0 = 0; i0 < 16; i0++) {
                if (i0 & mask) continue;
                const int i1 = i0 | mask;
                float2 a0 = amp[i0], a1 = amp[i1];
                amp[i0] = cadd(cmul(U00, a0), cmul(U01, a1));
                amp[i1] = cadd(cmul(U10, a0), cmul(U11, a1));
            }
        }
#pragma unroll
        for (int c = 0; c < NQ; c++) {
            const int t = (c + 1) & 3;
            const int cmsk = 8 >> c, tmsk = 8 >> t;
#pragma unroll
            for (int i = 0; i < 16; i++) {
                if ((i & cmsk) && !(i & tmsk)) {
                    float2 tmp = amp[i];
                    amp[i] = amp[i | tmsk];
                    amp[i | tmsk] = tmp;
                }
            }
        }
    }
}

// Kernel A: one tiny block computes U (16x16 complex) into global scratch.
__global__ void build_u_kernel(const float* __restrict__ qw, v2f* __restrict__ Ug) {
    const int tid = threadIdx.x;
    if (tid < 16) {
        float2 amp[16];
        build_u_col(qw, tid, amp);
#pragma unroll
        for (int i = 0; i < 16; i++) {
            v2f u; u.x = amp[i].x; u.y = amp[i].y;
            Ug[i * 16 + tid] = u;   // row-major [i][j]
        }
    }
}

// Main path. U is indexed with loop-constant addresses only -> uniform ->
// s_load into SGPRs (global pointer case). Templated so the LDS fallback
// keeps its address space.
template <typename UPtr>
__device__ __forceinline__ void vqc_main_body(const float* __restrict__ x,
                                              UPtr U,
                                              float* __restrict__ out, int B) {
    const int tid = threadIdx.x;
    const int base = blockIdx.x * (BLK * K) + tid;

    float4 xv[K];
    bool val[K];
#pragma unroll
    for (int k = 0; k < K; k++) {
        const int b = base + k * BLK;
        val[k] = (b < B);
        xv[k] = val[k] ? ((const float4*)x)[b] : make_float4(0.f, 0.f, 0.f, 0.f);
    }

    // RY encoding: tensor factors over wires (0,1) and (2,3).
    const float R = 0.07957747154594767f;   // 1/(4*pi): sin(x/2)=v_sin(x*R)
    float a01[K][4], a23[K][4];
#pragma unroll
    for (int k = 0; k < K; k++) {
        float s0 = __builtin_amdgcn_sinf(xv[k].x * R), c0 = __builtin_amdgcn_cosf(xv[k].x * R);
        float s1 = __builtin_amdgcn_sinf(xv[k].y * R), c1 = __builtin_amdgcn_cosf(xv[k].y * R);
        float s2 = __builtin_amdgcn_sinf(xv[k].z * R), c2 = __builtin_amdgcn_cosf(xv[k].z * R);
        float s3 = __builtin_amdgcn_sinf(xv[k].w * R), c3 = __builtin_amdgcn_cosf(xv[k].w * R);
        a01[k][0] = c0 * c1; a01[k][1] = c0 * s1; a01[k][2] = s0 * c1; a01[k][3] = s0 * s1;
        a23[k][0] = c2 * c3; a23[k][1] = c2 * s3; a23[k][2] = s2 * c3; a23[k][3] = s2 * s3;
    }
    // pack element-pairs into pk lanes: pair p = elements (2p, 2p+1)
    v2f a01p[2][4], a23p[2][4];
#pragma unroll
    for (int p = 0; p < 2; p++)
#pragma unroll
        for (int i = 0; i < 4; i++) {
            v2f t0; t0.x = a01[2 * p][i]; t0.y = a01[2 * p + 1][i]; a01p[p][i] = t0;
            v2f t1; t1.x = a23[2 * p][i]; t1.y = a23[2 * p + 1][i]; a23p[p][i] = t1;
        }

    v2f ow[4][2];   // [out wire][pair]
#pragma unroll
    for (int w = 0; w < 4; w++)
#pragma unroll
        for (int p = 0; p < 2; p++) ow[w][p] = (v2f)0.f;

#pragma unroll 1
    for (int iq = 0; iq < 4; iq++) {
        v2f accre[4][2], accim[4][2];
#pragma unroll
        for (int ii = 0; ii < 4; ii++)
#pragma unroll
            for (int p = 0; p < 2; p++) { accre[ii][p] = (v2f)0.f; accim[ii][p] = (v2f)0.f; }

#pragma unroll
        for (int j = 0; j < 16; j++) {
            v2f ps0 = pk_mul(a01p[0][j >> 2], a23p[0][j & 3]);
            v2f ps1 = pk_mul(a01p[1][j >> 2], a23p[1][j & 3]);
#pragma unroll
            for (int ii = 0; ii < 4; ii++) {
                const v2f u = U[(iq * 4 + ii) * 16 + j];  // uniform addr -> s_load
                pk_fma_lo_s(accre[ii][0], u, ps0);
                pk_fma_hi_s(accim[ii][0], u, ps0);
                pk_fma_lo_s(accre[ii][1], u, ps1);
                pk_fma_hi_s(accim[ii][1], u, ps1);
            }
        }

        // probs (packed over elements) + Walsh combine
#pragma unroll
        for (int p = 0; p < 2; p++) {
            v2f p0 = pk_mul(accre[0][p], accre[0][p]); pk_fma(p0, accim[0][p], accim[0][p]);
            v2f p1 = pk_mul(accre[1][p], accre[1][p]); pk_fma(p1, accim[1][p], accim[1][p]);
            v2f p2 = pk_mul(accre[2][p], accre[2][p]); pk_fma(p2, accim[2][p], accim[2][p]);
            v2f p3 = pk_mul(accre[3][p], accre[3][p]); pk_fma(p3, accim[3][p], accim[3][p]);
            v2f s01 = p0 + p1, d01 = p0 - p1;
            v2f s23 = p2 + p3, d23 = p2 - p3;
            v2f ssum = s01 + s23;
            ow[2][p] += s01 - s23;     // sign from bit1 of row
            ow[3][p] += d01 + d23;     // sign from bit0 of row
            if (iq & 2) ow[0][p] -= ssum; else ow[0][p] += ssum;   // bit3
            if (iq & 1) ow[1][p] -= ssum; else ow[1][p] += ssum;   // bit2
        }
    }

#pragma unroll
    for (int p = 0; p < 2; p++)
#pragma unroll
        for (int e = 0; e < 2; e++) {
            const int k = 2 * p + e;
            const int b = base + k * BLK;
            if (val[k]) {
                float4 o;
                o.x = (e == 0) ? ow[0][p].x : ow[0][p].y;
                o.y = (e == 0) ? ow[1][p].x : ow[1][p].y;
                o.z = (e == 0) ? ow[2][p].x : ow[2][p].y;
                o.w = (e == 0) ? ow[3][p].x : ow[3][p].y;
                ((float4*)out)[b] = o;
            }
        }
}

// Kernel B: U read directly from global scratch via scalar loads. No LDS.
__global__ __launch_bounds__(BLK) void vqc_main(const float* __restrict__ x,
                                                const v2f* __restrict__ Ug,
                                                float* __restrict__ out, int B) {
    vqc_main_body(x, Ug, out, B);
}

// Fallback if ws is too small: build U per block into LDS (normally unused).
__global__ void vqc_fused(const float* __restrict__ x, const float* __restrict__ qw,
                          float* __restrict__ out, int B) {
    __shared__ v2f Um[256];
    if (threadIdx.x < 16) {
        float2 amp[16];
        build_u_col(qw, threadIdx.x, amp);
#pragma unroll
        for (int i = 0; i < 16; i++) {
            v2f u; u.x = amp[i].x; u.y = amp[i].y;
            Um[i * 16 + threadIdx.x] = u;
        }
    }
    __syncthreads();
    vqc_main_body(x, (const v2f*)Um, out, B);
}

extern "C" void kernel_launch(void* const* d_in, const int* in_sizes, int n_in,
                              void* d_out, int out_size, void* d_ws, size_t ws_size,
                              hipStream_t stream) {
    const float* x  = (const float*)d_in[0];
    const float* qw = (const float*)d_in[1];
    float* out = (float*)d_out;
    const int B = in_sizes[0] / NQ;
    const int blocks = (B + BLK * K - 1) / (BLK * K);

    if (ws_size >= 256 * sizeof(v2f)) {
        v2f* Ug = (v2f*)d_ws;
        build_u_kernel<<<1, 64, 0, stream>>>(qw, Ug);
        vqc_main<<<blocks, BLK, 0, stream>>>(x, Ug, out, B);
    } else {
        vqc_fused<<<blocks, BLK, 0, stream>>>(x, qw, out, B);
    }
}

// Round 5
// 106.574 us; speedup vs baseline: 2.6334x; 1.0073x over previous
//
#include <hip/hip_runtime.h>

#define NQ 4
#define DEPTH 2
#define BLK 256
#define K 4           // elements per thread = 2 element-pairs packed in pk lanes

typedef float v2f  __attribute__((ext_vector_type(2)));
typedef float v16f __attribute__((ext_vector_type(16)));

// ---- forced packed-fp32 math ----
// u is wave-uniform {re,im} in an SGPR pair (VOP3P allows one scalar source).
__device__ __forceinline__ void pk_fma_lo_s(v2f& acc, v2f u, v2f b) {
    asm("v_pk_fma_f32 %0, %1, %2, %0 op_sel:[0,0,0] op_sel_hi:[0,1,1]"
        : "+v"(acc) : "s"(u), "v"(b));
}
__device__ __forceinline__ void pk_fma_hi_s(v2f& acc, v2f u, v2f b) {
    asm("v_pk_fma_f32 %0, %1, %2, %0 op_sel:[1,0,0] op_sel_hi:[1,1,1]"
        : "+v"(acc) : "s"(u), "v"(b));
}
__device__ __forceinline__ v2f pk_mul(v2f a, v2f b) {
    v2f d;
    asm("v_pk_mul_f32 %0, %1, %2" : "=v"(d) : "v"(a), "v"(b));
    return d;
}
__device__ __forceinline__ void pk_fma(v2f& acc, v2f a, v2f b) {
    asm("v_pk_fma_f32 %0, %1, %2, %0" : "+v"(acc) : "v"(a), "v"(b));
}

// Explicit wide scalar load of one U row (16 complex = 128 B) into SGPRs.
__device__ __forceinline__ void sload_row(const v2f* p, v16f& lo, v16f& hi) {
    asm volatile("s_load_dwordx16 %0, %2, 0x0\n\t"
                 "s_load_dwordx16 %1, %2, 0x40"
                 : "=s"(lo), "=s"(hi) : "s"(p) : "memory");
}
// Data-dependence-carrying waitcnt: any use of the tuples after this is ordered.
__device__ __forceinline__ void swait4(v16f& a, v16f& b, v16f& c, v16f& d) {
    asm volatile("s_waitcnt lgkmcnt(0)" : "+s"(a), "+s"(b), "+s"(c), "+s"(d));
}
// Extract complex pair q (compile-time q in 0..7) from an SGPR row half.
__device__ __forceinline__ v2f sg_pair(const v16f& r, int q) {
    v2f u; u.x = r[2 * q]; u.y = r[2 * q + 1]; return u;
}

__device__ __forceinline__ float2 cmul(float2 a, float2 b) {
    return make_float2(a.x * b.x - a.y * b.y, a.x * b.y + a.y * b.x);
}
__device__ __forceinline__ float2 cadd(float2 a, float2 b) {
    return make_float2(a.x + b.x, a.y + b.y);
}

// Simulate basis column `col` of the fixed post-encoding circuit unitary.
__device__ __forceinline__ void build_u_col(const float* __restrict__ qw, int col,
                                            float2 amp[16]) {
#pragma unroll
    for (int i = 0; i < 16; i++)
        amp[i] = make_float2((i == col) ? 1.f : 0.f, 0.f);

#pragma unroll
    for (int layer = 0; layer < DEPTH; layer++) {
#pragma unroll
        for (int w = 0; w < NQ; w++) {
            const float* g = qw + (layer * NQ + w) * 3;
            float phi = g[0], theta = g[1], omega = g[2];
            float ch, sh, sp, cp, sm, cm;
            __sincosf(0.5f * theta, &sh, &ch);
            __sincosf(-0.5f * (phi + omega), &sp, &cp);
            __sincosf(0.5f * (phi - omega), &sm, &cm);
            float2 U00 = make_float2(cp * ch, sp * ch);
            float2 U01 = make_float2(-cm * sh, -sm * sh);
            float2 U10 = make_float2(cm * sh, -sm * sh);
            float2 U11 = make_float2(cp * ch, -sp * ch);
            const int mask = 8 >> w;
#pragma unroll
            for (int i0 = 0; i0 < 16; i0++) {
                if (i0 & mask) continue;
                const int i1 = i0 | mask;
                float2 a0 = amp[i0], a1 = amp[i1];
                amp[i0] = cadd(cmul(U00, a0), cmul(U01, a1));
                amp[i1] = cadd(cmul(U10, a0), cmul(U11, a1));
            }
        }
#pragma unroll
        for (int c = 0; c < NQ; c++) {
            const int t = (c + 1) & 3;
            const int cmsk = 8 >> c, tmsk = 8 >> t;
#pragma unroll
            for (int i = 0; i < 16; i++) {
                if ((i & cmsk) && !(i & tmsk)) {
                    float2 tmp = amp[i];
                    amp[i] = amp[i | tmsk];
                    amp[i | tmsk] = tmp;
                }
            }
        }
    }
}

// Kernel A: one tiny block computes U (16x16 complex) into global scratch.
__global__ void build_u_kernel(const float* __restrict__ qw, v2f* __restrict__ Ug) {
    const int tid = threadIdx.x;
    if (tid < 16) {
        float2 amp[16];
        build_u_col(qw, tid, amp);
#pragma unroll
        for (int i = 0; i < 16; i++) {
            v2f u; u.x = amp[i].x; u.y = amp[i].y;
            Ug[i * 16 + tid] = u;   // row-major [i][j]
        }
    }
}

// ---- encoding helper: build ps tables (element-pair-packed psi values) ----
__device__ __forceinline__ void build_ps(const float* __restrict__ x, int base, int B,
                                         v2f ps[2][16], bool val[K]) {
    float4 xv[K];
#pragma unroll
    for (int k = 0; k < K; k++) {
        const int b = base + k * BLK;
        val[k] = (b < B);
        xv[k] = val[k] ? ((const float4*)x)[b] : make_float4(0.f, 0.f, 0.f, 0.f);
    }
    const float R = 0.07957747154594767f;   // 1/(4*pi): sin(x/2)=v_sin(x*R)
    float a01[K][4], a23[K][4];
#pragma unroll
    for (int k = 0; k < K; k++) {
        float s0 = __builtin_amdgcn_sinf(xv[k].x * R), c0 = __builtin_amdgcn_cosf(xv[k].x * R);
        float s1 = __builtin_amdgcn_sinf(xv[k].y * R), c1 = __builtin_amdgcn_cosf(xv[k].y * R);
        float s2 = __builtin_amdgcn_sinf(xv[k].z * R), c2 = __builtin_amdgcn_cosf(xv[k].z * R);
        float s3 = __builtin_amdgcn_sinf(xv[k].w * R), c3 = __builtin_amdgcn_cosf(xv[k].w * R);
        a01[k][0] = c0 * c1; a01[k][1] = c0 * s1; a01[k][2] = s0 * c1; a01[k][3] = s0 * s1;
        a23[k][0] = c2 * c3; a23[k][1] = c2 * s3; a23[k][2] = s2 * c3; a23[k][3] = s2 * s3;
    }
#pragma unroll
    for (int p = 0; p < 2; p++)
#pragma unroll
        for (int j = 0; j < 16; j++) {
            v2f t0; t0.x = a01[2 * p][j >> 2]; t0.y = a01[2 * p + 1][j >> 2];
            v2f t1; t1.x = a23[2 * p][j & 3]; t1.y = a23[2 * p + 1][j & 3];
            ps[p][j] = pk_mul(t0, t1);
        }
}

__device__ __forceinline__ void store_out(float* __restrict__ out, int base, int B,
                                          const bool val[K], v2f ow[4][2]) {
#pragma unroll
    for (int p = 0; p < 2; p++)
#pragma unroll
        for (int e = 0; e < 2; e++) {
            const int k = 2 * p + e;
            const int b = base + k * BLK;
            if (val[k]) {
                float4 o;
                o.x = (e == 0) ? ow[0][p].x : ow[0][p].y;
                o.y = (e == 0) ? ow[1][p].x : ow[1][p].y;
                o.z = (e == 0) ? ow[2][p].x : ow[2][p].y;
                o.w = (e == 0) ? ow[3][p].x : ow[3][p].y;
                ((float4*)out)[b] = o;
            }
        }
}

// Kernel B: U rows streamed through SGPRs via explicit s_load_dwordx16;
// inner loop is pure v_pk_fma_f32 (one SGPR-pair source). No LDS, no VMEM.
__global__ __launch_bounds__(BLK) void vqc_main(const float* __restrict__ x,
                                                const v2f* __restrict__ Ug,
                                                float* __restrict__ out, int B) {
    const int tid = threadIdx.x;
    const int base = blockIdx.x * (BLK * K) + tid;

    v2f ps[2][16];
    bool val[K];
    build_ps(x, base, B, ps, val);

    v2f ow[4][2];
#pragma unroll
    for (int w = 0; w < 4; w++)
#pragma unroll
        for (int p = 0; p < 2; p++) ow[w][p] = (v2f)0.f;

#pragma unroll 1
    for (int iq = 0; iq < 4; iq++) {
        v2f P[4][2];
#pragma unroll
        for (int t = 0; t < 2; t++) {           // row-pair within quad
            const int r0 = iq * 4 + t * 2;
            v16f alo, ahi, blo, bhi;
            sload_row(Ug + r0 * 16, alo, ahi);
            sload_row(Ug + (r0 + 1) * 16, blo, bhi);
            swait4(alo, ahi, blo, bhi);

            v2f are[2], aim[2], bre[2], bim[2];
#pragma unroll
            for (int p = 0; p < 2; p++) {
                are[p] = (v2f)0.f; aim[p] = (v2f)0.f;
                bre[p] = (v2f)0.f; bim[p] = (v2f)0.f;
            }
#pragma unroll
            for (int j = 0; j < 16; j++) {
                const v2f ua = sg_pair((j < 8) ? alo : ahi, j & 7);
                const v2f ub = sg_pair((j < 8) ? blo : bhi, j & 7);
#pragma unroll
                for (int p = 0; p < 2; p++) {
                    pk_fma_lo_s(are[p], ua, ps[p][j]);
                    pk_fma_hi_s(aim[p], ua, ps[p][j]);
                    pk_fma_lo_s(bre[p], ub, ps[p][j]);
                    pk_fma_hi_s(bim[p], ub, ps[p][j]);
                }
            }
#pragma unroll
            for (int p = 0; p < 2; p++) {
                v2f pa = pk_mul(are[p], are[p]); pk_fma(pa, aim[p], aim[p]);
                v2f pb = pk_mul(bre[p], bre[p]); pk_fma(pb, bim[p], bim[p]);
                P[t * 2][p] = pa;
                P[t * 2 + 1][p] = pb;
            }
        }

        // quad-Walsh combine
#pragma unroll
        for (int p = 0; p < 2; p++) {
            v2f p0 = P[0][p], p1 = P[1][p], p2 = P[2][p], p3 = P[3][p];
            v2f s01 = p0 + p1, d01 = p0 - p1;
            v2f s23 = p2 + p3, d23 = p2 - p3;
            v2f ssum = s01 + s23;
            ow[2][p] += s01 - s23;     // sign from bit1 of row
            ow[3][p] += d01 + d23;     // sign from bit0 of row
            if (iq & 2) ow[0][p] -= ssum; else ow[0][p] += ssum;   // bit3
            if (iq & 1) ow[1][p] -= ssum; else ow[1][p] += ssum;   // bit2
        }
    }

    store_out(out, base, B, val, ow);
}

// Fallback if ws is too small (normally unused): build U per block into LDS
// and run a straightforward per-j vector-load path.
__global__ void vqc_fused(const float* __restrict__ x, const float* __restrict__ qw,
                          float* __restrict__ out, int B) {
    __shared__ v2f Um[256];
    if (threadIdx.x < 16) {
        float2 amp[16];
        build_u_col(qw, threadIdx.x, amp);
#pragma unroll
        for (int i = 0; i < 16; i++) {
            v2f u; u.x = amp[i].x; u.y = amp[i].y;
            Um[i * 16 + threadIdx.x] = u;
        }
    }
    __syncthreads();

    const int tid = threadIdx.x;
    const int base = blockIdx.x * (BLK * K) + tid;
    v2f ps[2][16];
    bool val[K];
    build_ps(x, base, B, ps, val);

    v2f ow[4][2];
#pragma unroll
    for (int w = 0; w < 4; w++)
#pragma unroll
        for (int p = 0; p < 2; p++) ow[w][p] = (v2f)0.f;

#pragma unroll 1
    for (int iq = 0; iq < 4; iq++) {
        v2f P[4][2];
#pragma unroll
        for (int ii = 0; ii < 4; ii++) {
            v2f re[2] = {(v2f)0.f, (v2f)0.f}, im[2] = {(v2f)0.f, (v2f)0.f};
#pragma unroll
            for (int j = 0; j < 16; j++) {
                const v2f u = Um[(iq * 4 + ii) * 16 + j];
#pragma unroll
                for (int p = 0; p < 2; p++) {
                    v2f ur; ur.x = u.x; ur.y = u.x;
                    v2f ui; ui.x = u.y; ui.y = u.y;
                    pk_fma(re[p], ur, ps[p][j]);
                    pk_fma(im[p], ui, ps[p][j]);
                }
            }
#pragma unroll
            for (int p = 0; p < 2; p++) {
                v2f pr = pk_mul(re[p], re[p]); pk_fma(pr, im[p], im[p]);
                P[ii][p] = pr;
            }
        }
#pragma unroll
        for (int p = 0; p < 2; p++) {
            v2f p0 = P[0][p], p1 = P[1][p], p2 = P[2][p], p3 = P[3][p];
            v2f s01 = p0 + p1, d01 = p0 - p1;
            v2f s23 = p2 + p3, d23 = p2 - p3;
            v2f ssum = s01 + s23;
            ow[2][p] += s01 - s23;
            ow[3][p] += d01 + d23;
            if (iq & 2) ow[0][p] -= ssum; else ow[0][p] += ssum;
            if (iq & 1) ow[1][p] -= ssum; else ow[1][p] += ssum;
        }
    }
    store_out(out, base, B, val, ow);
}

extern "C" void kernel_launch(void* const* d_in, const int* in_sizes, int n_in,
                              void* d_out, int out_size, void* d_ws, size_t ws_size,
                              hipStream_t stream) {
    const float* x  = (const float*)d_in[0];
    const float* qw = (const float*)d_in[1];
    float* out = (float*)d_out;
    const int B = in_sizes[0] / NQ;
    const int blocks = (B + BLK * K - 1) / (BLK * K);

    if (ws_size >= 256 * sizeof(v2f)) {
        v2f* Ug = (v2f*)d_ws;
        build_u_kernel<<<1, 64, 0, stream>>>(qw, Ug);
        vqc_main<<<blocks, BLK, 0, stream>>>(x, Ug, out, B);
    } else {
        vqc_fused<<<blocks, BLK, 0, stream>>>(x, qw, out, B);
    }
}